// Round 6
// baseline (219.088 us; speedup 1.0000x reference)
//
#include <hip/hip_runtime.h>
#include <float.h>
#include <math.h>

// Problem constants: B=16, L=1024, D=512, DH=64, H=8, ktop=13
#define PROJ_N (16*64*1024)   // 1048576 floats per projected tensor (layout [b*64+d][l])

using short8_t  = __attribute__((ext_vector_type(8)))  short;
using uint4_t   = __attribute__((ext_vector_type(4)))  unsigned;
using floatx16  = __attribute__((ext_vector_type(16))) float;

// ---------------------------------------------------------------------------
// bf16 helpers: RNE round, pack, and hi/lo split (x = hi + lo)
// ---------------------------------------------------------------------------
__device__ __forceinline__ unsigned bf16r(float x) {
  unsigned u = __float_as_uint(x);
  return (u + 0x7FFFu + ((u >> 16) & 1u)) >> 16;
}
__device__ __forceinline__ unsigned pk_bf16(float x, float y) {
  return bf16r(x) | (bf16r(y) << 16);
}
// split 8 floats into hi/lo bf16 short8 fragments
__device__ __forceinline__ void split8(float4 a, float4 b, short8_t& h, short8_t& l) {
  float f[8] = {a.x, a.y, a.z, a.w, b.x, b.y, b.z, b.w};
  unsigned hp[4], lp[4];
#pragma unroll
  for (int j = 0; j < 4; ++j) {
    unsigned h0 = bf16r(f[2*j]), h1 = bf16r(f[2*j+1]);
    hp[j] = h0 | (h1 << 16);
    float l0 = f[2*j]   - __uint_as_float(h0 << 16);
    float l1 = f[2*j+1] - __uint_as_float(h1 << 16);
    lp[j] = pk_bf16(l0, l1);
  }
  uint4_t hv = {hp[0], hp[1], hp[2], hp[3]};
  uint4_t lv = {lp[0], lp[1], lp[2], lp[3]};
  h = __builtin_bit_cast(short8_t, hv);
  l = __builtin_bit_cast(short8_t, lv);
}

// ---------------------------------------------------------------------------
// Kernel W: Wt_h/Wt_l[d][k] = hi/lo bf16 split of Wq[k][d]  (64 x 512, 128 KB)
// Tiny prelude; result is L2-resident and reused by every proj block.
// ---------------------------------------------------------------------------
__global__ __launch_bounds__(256) void wtrans_kernel(
    const float* __restrict__ Wq, unsigned short* __restrict__ Wth,
    unsigned short* __restrict__ Wtl) {
  const int tg = blockIdx.x * 256 + threadIdx.x;   // 0..32767
  const int d = tg & 63, k = tg >> 6;
  const float x = Wq[k * 64 + d];
  const unsigned h = bf16r(x);
  const float lo = x - __uint_as_float(h << 16);
  Wth[d * 512 + k] = (unsigned short)h;
  Wtl[d * 512 + k] = (unsigned short)bf16r(lo);
}

// ---------------------------------------------------------------------------
// Kernel A: proj = X @ Wq + bq via split-precision bf16 MFMA, LDS-free loads.
// grid = 1536 (3 inputs x 512 tiles of 32 l), block = 256 (4 waves).
// Wave (dh = w&1, kh = w>>1): 32 l x 32 d-half x K=256-half, 16 k-steps.
//   A-operand = Wt[d][k] hi/lo (direct 16B global loads, L2-resident)
//   B-operand = X[l][k]  (natural layout; 2x16B loads + split)
// Explicit 1-deep register prefetch of next k-step's X and Wt fragments.
// Cross-K reduction via LDS; epilogue by kh==0 waves, coalesced stores.
// ---------------------------------------------------------------------------
__global__ __launch_bounds__(256) void proj_kernel(
    const float* __restrict__ Q, const float* __restrict__ K,
    const float* __restrict__ V, const unsigned short* __restrict__ Wth,
    const unsigned short* __restrict__ Wtl, const float* __restrict__ bq,
    float* __restrict__ proj) {
  __shared__ float red[2][2048];

  const int blk  = blockIdx.x;
  const int in   = blk >> 9;            // 0..2
  const int row0 = (blk & 511) << 5;    // global row (b*1024 + l), 32-row tile
  const float* __restrict__ X = (in == 0) ? Q : (in == 1 ? K : V);

  const int tid  = threadIdx.x;
  const int w    = tid >> 6;
  const int dh   = w & 1;               // d-half
  const int kh   = w >> 1;              // K-half
  const int lane = tid & 63;
  const int col  = lane & 31;           // l for B / d-row for A
  const int hk   = lane >> 5;

  const float* __restrict__ xrow = X + (size_t)(row0 + col) * 512;
  const unsigned short* __restrict__ whp = Wth + (size_t)((dh << 5) + col) * 512;
  const unsigned short* __restrict__ wlp = Wtl + (size_t)((dh << 5) + col) * 512;
  const int kbase = (kh << 8) + (hk << 3);

  floatx16 acc0 = {0.f,0.f,0.f,0.f,0.f,0.f,0.f,0.f,
                   0.f,0.f,0.f,0.f,0.f,0.f,0.f,0.f};
  floatx16 acc1 = {0.f,0.f,0.f,0.f,0.f,0.f,0.f,0.f,
                   0.f,0.f,0.f,0.f,0.f,0.f,0.f,0.f};

  float4   xa = *(const float4*)&xrow[kbase];
  float4   xb = *(const float4*)&xrow[kbase + 4];
  short8_t ah = *(const short8_t*)&whp[kbase];
  short8_t al = *(const short8_t*)&wlp[kbase];

#pragma unroll
  for (int ks = 0; ks < 16; ++ks) {
    float4 nxa, nxb; short8_t nah, nal;
    if (ks < 15) {
      const int kn = kbase + ((ks + 1) << 4);
      nxa = *(const float4*)&xrow[kn];
      nxb = *(const float4*)&xrow[kn + 4];
      nah = *(const short8_t*)&whp[kn];
      nal = *(const short8_t*)&wlp[kn];
    }
    short8_t bh, bl;
    split8(xa, xb, bh, bl);
    acc0 = __builtin_amdgcn_mfma_f32_32x32x16_bf16(ah, bh, acc0, 0, 0, 0);
    acc1 = __builtin_amdgcn_mfma_f32_32x32x16_bf16(ah, bl, acc1, 0, 0, 0);
    acc1 = __builtin_amdgcn_mfma_f32_32x32x16_bf16(al, bh, acc1, 0, 0, 0);
    if (ks < 15) { xa = nxa; xb = nxb; ah = nah; al = nal; }
  }

  // ---- cross-K reduction via LDS; C/D: col=lane&31=l, m=(r&3)+8*(r>>2)+4*hk
  if (kh == 1) {
#pragma unroll
    for (int r = 0; r < 16; ++r) {
      const int m = (r & 3) + ((r >> 2) << 3) + (hk << 2);
      red[dh][(m << 5) + col] = acc0[r] + acc1[r];
    }
  }
  __syncthreads();
  if (kh == 0) {
    const int b    = row0 >> 10;
    const int lloc = (row0 & 1023) + col;
    float* __restrict__ p = proj + (size_t)in * PROJ_N
                          + (((size_t)b << 6) << 10) + lloc;
#pragma unroll
    for (int r = 0; r < 16; ++r) {
      const int m = (r & 3) + ((r >> 2) << 3) + (hk << 2);
      const int d = (dh << 5) + m;
      p[(size_t)d << 10] = acc0[r] + acc1[r] + red[dh][(m << 5) + col] + bq[d];
    }
  }
}

// ---------------------------------------------------------------------------
// Kernel B: circular correlation via SPLIT-PRECISION bf16 MFMA + top-13 +
// softmax + FUSED v-aggregation. One block per (b,d) pair; 4 waves split K.
//   corr[col + 32*row] = sum_kk k_ext[1024+kk-32row] * q_ext[kk+col]
// Then agg[l] = sum_k w_k * v[(l+idx_k) mod 1024]  (v staged in reused LDS).
// ---------------------------------------------------------------------------
__global__ __launch_bounds__(256) void corr_mfma_kernel(
    const float* __restrict__ qp, const float* __restrict__ kp,
    const float* __restrict__ vp, float* __restrict__ agg) {
  __shared__ __align__(16) short qh[2048];   // q_ext hi, linear lines
  __shared__ __align__(16) short ql[2048];   // q_ext lo, linear lines
  __shared__ __align__(16) short kh[2048];   // k_ext hi, line c at phys c^((c>>3)&7)
  __shared__ __align__(16) short kl[2048];   // k_ext lo, swizzled
  __shared__ float corr4[4][1024];           // partials; later reused as vs[2048]
  __shared__ float tv[13];
  __shared__ float sw[13];
  __shared__ int   ts[13];
  __shared__ float rv[4];
  __shared__ int   rs[4];
  __shared__ int   bsh;

  const int pair = blockIdx.x;
  const int tid  = threadIdx.x;
  const int w    = tid >> 6;
  const int lane = tid & 63;
  const int row  = lane & 31;
  const int hk2  = lane >> 5;

  const float* __restrict__ qg = qp + (size_t)pair * 1024;
  const float* __restrict__ kg = kp + (size_t)pair * 1024;
  const float* __restrict__ vg = vp + (size_t)pair * 1024;

  // ---- stage q_ext and k_ext as hi/lo bf16 pairs ----
  {
    const int j = (tid << 3) & 1023;          // both exts are periodic copies
    float4 a0 = *(const float4*)&qg[j];
    float4 a1 = *(const float4*)&qg[j + 4];
    short8_t h8, l8;
    split8(a0, a1, h8, l8);
    *(short8_t*)&qh[tid << 3] = h8;
    *(short8_t*)&ql[tid << 3] = l8;
    float4 b0 = *(const float4*)&kg[j];
    float4 b1 = *(const float4*)&kg[j + 4];
    split8(b0, b1, h8, l8);
    const int p = tid ^ ((tid >> 3) & 7);
    *(short8_t*)&kh[p << 3] = h8;
    *(short8_t*)&kl[p << 3] = l8;
  }
  __syncthreads();

  // ---- MFMA over this wave's K-chunk (3 products per step) ----
  floatx16 acc = {0.f,0.f,0.f,0.f,0.f,0.f,0.f,0.f,
                  0.f,0.f,0.f,0.f,0.f,0.f,0.f,0.f};
  const unsigned* __restrict__ qhd = (const unsigned*)qh;
  const unsigned* __restrict__ qld = (const unsigned*)ql;
#pragma unroll
  for (int i = 0; i < 16; ++i) {
    const int k0 = (w << 8) + (i << 4);
    // A fragments: k_ext[1024 + k0 + 8*hk2 - 32*row .. +7]
    const int e0 = 1024 + k0 + (hk2 << 3) - (row << 5);
    const int c  = e0 >> 3;
    const int p  = c ^ ((c >> 3) & 7);
    short8_t ah = *(const short8_t*)&kh[p << 3];
    short8_t al = *(const short8_t*)&kl[p << 3];
    // B fragments: q_ext[k0 + 8*hk2 + row .. +7]  (element-misaligned)
    const int s0 = k0 + (hk2 << 3) + row;
    const int d0 = s0 >> 1;
    const unsigned sh = (s0 & 1) << 4;
    unsigned w0 = qhd[d0 + 0], w1 = qhd[d0 + 1], w2 = qhd[d0 + 2],
             w3 = qhd[d0 + 3], w4 = qhd[d0 + 4];
    uint4_t buh = { __builtin_amdgcn_alignbit(w1, w0, sh),
                    __builtin_amdgcn_alignbit(w2, w1, sh),
                    __builtin_amdgcn_alignbit(w3, w2, sh),
                    __builtin_amdgcn_alignbit(w4, w3, sh) };
    unsigned x0 = qld[d0 + 0], x1 = qld[d0 + 1], x2 = qld[d0 + 2],
             x3 = qld[d0 + 3], x4 = qld[d0 + 4];
    uint4_t bul = { __builtin_amdgcn_alignbit(x1, x0, sh),
                    __builtin_amdgcn_alignbit(x2, x1, sh),
                    __builtin_amdgcn_alignbit(x3, x2, sh),
                    __builtin_amdgcn_alignbit(x4, x3, sh) };
    short8_t bh = __builtin_bit_cast(short8_t, buh);
    short8_t bl = __builtin_bit_cast(short8_t, bul);
    acc = __builtin_amdgcn_mfma_f32_32x32x16_bf16(ah, bh, acc, 0, 0, 0);
    acc = __builtin_amdgcn_mfma_f32_32x32x16_bf16(ah, bl, acc, 0, 0, 0);
    acc = __builtin_amdgcn_mfma_f32_32x32x16_bf16(al, bh, acc, 0, 0, 0);
  }

  // ---- write partials; C/D layout: col=lane&31, row=(r&3)+8*(r>>2)+4*hk2 ----
#pragma unroll
  for (int r = 0; r < 16; ++r) {
    const int srow = (r & 3) + ((r >> 2) << 3) + (hk2 << 2);
    corr4[w][(srow << 5) | row] = acc[r];
  }
  __syncthreads();

  // ---- issue v loads early (T14): latency hides under reduce+topk ----
  float4 vl0 = *(const float4*)&vg[(4 * tid) & 1023];
  float4 vl1 = *(const float4*)&vg[(4 * (tid + 256)) & 1023];

  // ---- reduce 4 partials; each thread owns s = {tid, +256, +512, +768} ----
  float v0 = corr4[0][tid]       + corr4[1][tid]       + corr4[2][tid]       + corr4[3][tid];
  float v1 = corr4[0][tid + 256] + corr4[1][tid + 256] + corr4[2][tid + 256] + corr4[3][tid + 256];
  float v2 = corr4[0][tid + 512] + corr4[1][tid + 512] + corr4[2][tid + 512] + corr4[3][tid + 512];
  float v3 = corr4[0][tid + 768] + corr4[1][tid + 768] + corr4[2][tid + 768] + corr4[3][tid + 768];
  __syncthreads();   // all corr4 reads done; safe to reuse as vs

  // ---- stage v (duplicated to 2048) into reused corr4 space ----
  float* vs = &corr4[0][0];
  *(float4*)&vs[4 * tid]         = vl0;
  *(float4*)&vs[4 * (tid + 256)] = vl1;

  // ---- top-13 via iterative block argmax ----
  for (int r = 0; r < 13; ++r) {
    float bv = v0; int bs = tid;
    if (v1 > bv) { bv = v1; bs = tid + 256; }
    if (v2 > bv) { bv = v2; bs = tid + 512; }
    if (v3 > bv) { bv = v3; bs = tid + 768; }
#pragma unroll
    for (int off = 32; off >= 1; off >>= 1) {
      float ov = __shfl_xor(bv, off, 64);
      int   os = __shfl_xor(bs, off, 64);
      if (ov > bv || (ov == bv && os < bs)) { bv = ov; bs = os; }
    }
    if (lane == 0) { rv[w] = bv; rs[w] = bs; }
    __syncthreads();
    if (tid == 0) {
      float cv = rv[0]; int cs = rs[0];
#pragma unroll
      for (int u = 1; u < 4; ++u)
        if (rv[u] > cv || (rv[u] == cv && rs[u] < cs)) { cv = rv[u]; cs = rs[u]; }
      tv[r] = cv; ts[r] = cs; bsh = cs;
    }
    __syncthreads();
    const int bw = bsh;
    if ((bw & 255) == tid) {
      const int slot = bw >> 8;
      if      (slot == 0) v0 = -FLT_MAX;
      else if (slot == 1) v1 = -FLT_MAX;
      else if (slot == 2) v2 = -FLT_MAX;
      else                v3 = -FLT_MAX;
    }
  }

  // ---- softmax over the 13 values (thread 0) ----
  if (tid == 0) {
    const float mx = tv[0];
    float e[13]; float s = 0.f;
#pragma unroll
    for (int k2 = 0; k2 < 13; ++k2) { e[k2] = __expf(tv[k2] - mx); s += e[k2]; }
    const float inv = 1.f / s;
#pragma unroll
    for (int k2 = 0; k2 < 13; ++k2) sw[k2] = e[k2] * inv;
  }
  __syncthreads();

  // ---- fused aggregation: agg[l] = sum_k w_k * v[(l+idx_k) mod 1024] ----
  float r0 = 0.f, r1 = 0.f, r2 = 0.f, r3 = 0.f;
#pragma unroll
  for (int k2 = 0; k2 < 13; ++k2) {
    const float wk = sw[k2];
    const int   ik = ts[k2];
    r0 += wk * vs[tid        + ik];
    r1 += wk * vs[tid + 256  + ik];
    r2 += wk * vs[tid + 512  + ik];
    r3 += wk * vs[tid + 768  + ik];
  }
  float* __restrict__ ag = agg + (size_t)pair * 1024;
  ag[tid] = r0; ag[tid + 256] = r1; ag[tid + 512] = r2; ag[tid + 768] = r3;
}

// ---------------------------------------------------------------------------
// Kernel D: out[b][l][h*64+d] = agg[b*64+d][l]  (transpose + 8x head copy)
// ---------------------------------------------------------------------------
__global__ __launch_bounds__(256) void out_kernel(
    const float* __restrict__ agg, float* __restrict__ out) {
  __shared__ float tile[64][65];
  const int blk = blockIdx.x;
  const int b = blk >> 4, lt = blk & 15;
  const int l0 = lt * 64;
  const int t = threadIdx.x;
  const int j = t & 63, qq = t >> 6;

#pragma unroll
  for (int p = 0; p < 16; ++p) {
    const int d = p * 4 + qq;
    tile[d][j] = agg[(size_t)(b * 64 + d) * 1024 + l0 + j];
  }
  __syncthreads();
#pragma unroll
  for (int p = 0; p < 16; ++p) {
    const int jj = p * 4 + qq;
    const float val = tile[j][jj];
    const size_t rowbase = ((size_t)(b * 1024 + l0 + jj)) * 512;
#pragma unroll
    for (int h = 0; h < 8; ++h)
      out[rowbase + h * 64 + j] = val;
  }
}

// ---------------------------------------------------------------------------
extern "C" void kernel_launch(void* const* d_in, const int* in_sizes, int n_in,
                              void* d_out, int out_size, void* d_ws, size_t ws_size,
                              hipStream_t stream) {
  const float* Q  = (const float*)d_in[0];
  const float* K  = (const float*)d_in[1];
  const float* V  = (const float*)d_in[2];
  const float* Wq = (const float*)d_in[3];
  const float* bq = (const float*)d_in[4];
  float* out = (float*)d_out;
  float* ws  = (float*)d_ws;

  float* proj = ws;                               // 3 * 1048576 floats
  float* agg  = ws + (size_t)3 * PROJ_N;          // 1048576 floats
  // Wt_h/Wt_l (128 KB) live at agg's base: read only by proj_kernel, then
  // overwritten by corr's agg stores (kernels are stream-serialized).
  unsigned short* Wth = (unsigned short*)agg;     // 64*512 shorts
  unsigned short* Wtl = Wth + 64 * 512;

  wtrans_kernel<<<128, 256, 0, stream>>>(Wq, Wth, Wtl);
  proj_kernel<<<1536, 256, 0, stream>>>(Q, K, V, Wth, Wtl, bq, proj);
  corr_mfma_kernel<<<1024, 256, 0, stream>>>(proj, proj + PROJ_N,
                                             proj + (size_t)2 * PROJ_N, agg);
  out_kernel<<<256, 256, 0, stream>>>(agg, out);
}

// Round 7
// 192.620 us; speedup vs baseline: 1.1374x; 1.1374x over previous
//
#include <hip/hip_runtime.h>
#include <float.h>
#include <math.h>

// Problem constants: B=16, L=1024, D=512, DH=64, H=8, ktop=13
#define PROJ_N (16*64*1024)   // 1048576 floats per projected tensor (layout [b*64+d][l])

using short8_t  = __attribute__((ext_vector_type(8)))  short;
using uint4_t   = __attribute__((ext_vector_type(4)))  unsigned;
using floatx16  = __attribute__((ext_vector_type(16))) float;

// ---------------------------------------------------------------------------
// bf16 helpers: RNE round, pack, and hi/lo split (x = hi + lo)
// ---------------------------------------------------------------------------
__device__ __forceinline__ unsigned bf16r(float x) {
  unsigned u = __float_as_uint(x);
  return (u + 0x7FFFu + ((u >> 16) & 1u)) >> 16;
}
__device__ __forceinline__ unsigned pk_bf16(float x, float y) {
  return bf16r(x) | (bf16r(y) << 16);
}
// split 8 floats into hi/lo bf16 short8 fragments
__device__ __forceinline__ void split8(float4 a, float4 b, short8_t& h, short8_t& l) {
  float f[8] = {a.x, a.y, a.z, a.w, b.x, b.y, b.z, b.w};
  unsigned hp[4], lp[4];
#pragma unroll
  for (int j = 0; j < 4; ++j) {
    unsigned h0 = bf16r(f[2*j]), h1 = bf16r(f[2*j+1]);
    hp[j] = h0 | (h1 << 16);
    float l0 = f[2*j]   - __uint_as_float(h0 << 16);
    float l1 = f[2*j+1] - __uint_as_float(h1 << 16);
    lp[j] = pk_bf16(l0, l1);
  }
  uint4_t hv = {hp[0], hp[1], hp[2], hp[3]};
  uint4_t lv = {lp[0], lp[1], lp[2], lp[3]};
  h = __builtin_bit_cast(short8_t, hv);
  l = __builtin_bit_cast(short8_t, lv);
}

// ---------------------------------------------------------------------------
// Kernel W: Wt_h/Wt_l[d][k] = hi/lo bf16 split of Wq[k][d]  (64 x 512, 128 KB)
// ---------------------------------------------------------------------------
__global__ __launch_bounds__(256) void wtrans_kernel(
    const float* __restrict__ Wq, unsigned short* __restrict__ Wth,
    unsigned short* __restrict__ Wtl) {
  const int tg = blockIdx.x * 256 + threadIdx.x;   // 0..32767
  const int d = tg & 63, k = tg >> 6;
  const float x = Wq[k * 64 + d];
  const unsigned h = bf16r(x);
  const float lo = x - __uint_as_float(h << 16);
  Wth[d * 512 + k] = (unsigned short)h;
  Wtl[d * 512 + k] = (unsigned short)bf16r(lo);
}

// ---------------------------------------------------------------------------
// Kernel A: proj = X @ Wq + bq via split-precision bf16 MFMA, LDS-free.
// ROUND-5 GEOMETRY (the 52 us config): grid = 768 (3 x 256 tiles of 64 l),
// block = 128 (2 waves x 32 l), full K=512 per wave (32 k-steps x 6 MFMA).
// THIS ROUND: __launch_bounds__(128,1) frees the register allocator +
// explicit 4-deep X / 2-deep W register prefetch in a fully-unrolled loop
// (ILP covers HBM latency; the 1536-wave grid can't provide TLP).
// ---------------------------------------------------------------------------
__global__ __launch_bounds__(128, 1) void proj_kernel(
    const float* __restrict__ Q, const float* __restrict__ K,
    const float* __restrict__ V, const unsigned short* __restrict__ Wth,
    const unsigned short* __restrict__ Wtl, const float* __restrict__ bq,
    float* __restrict__ proj) {
  const int blk  = blockIdx.x;
  const int in   = blk >> 8;            // 0..2
  const int row0 = (blk & 255) << 6;    // global row (b*1024 + l), 64-row tile
  const float* __restrict__ X = (in == 0) ? Q : (in == 1 ? K : V);

  const int tid  = threadIdx.x;
  const int w    = tid >> 6;
  const int lane = tid & 63;
  const int col  = lane & 31;   // l within wave tile / d-row for A
  const int hk   = lane >> 5;

  const int lrow = row0 + w * 32 + col;
  const float* __restrict__ xrow = X + (size_t)lrow * 512;
  const unsigned short* __restrict__ wh0 = Wth + (size_t)col * 512;
  const unsigned short* __restrict__ wl0 = Wtl + (size_t)col * 512;
  const unsigned short* __restrict__ wh1 = wh0 + 32 * 512;
  const unsigned short* __restrict__ wl1 = wl0 + 32 * 512;

  floatx16 acc0 = {0.f,0.f,0.f,0.f,0.f,0.f,0.f,0.f,
                   0.f,0.f,0.f,0.f,0.f,0.f,0.f,0.f};
  floatx16 acc1 = {0.f,0.f,0.f,0.f,0.f,0.f,0.f,0.f,
                   0.f,0.f,0.f,0.f,0.f,0.f,0.f,0.f};

  // explicit register prefetch pipelines (fully static after unroll)
  float4   pxa[4], pxb[4];
  short8_t pa0h[2], pa0l[2], pa1h[2], pa1l[2];
#pragma unroll
  for (int i = 0; i < 4; ++i) {
    const int k0 = (i << 4) + (hk << 3);
    pxa[i] = *(const float4*)&xrow[k0];
    pxb[i] = *(const float4*)&xrow[k0 + 4];
  }
#pragma unroll
  for (int i = 0; i < 2; ++i) {
    const int k0 = (i << 4) + (hk << 3);
    pa0h[i] = *(const short8_t*)&wh0[k0];
    pa0l[i] = *(const short8_t*)&wl0[k0];
    pa1h[i] = *(const short8_t*)&wh1[k0];
    pa1l[i] = *(const short8_t*)&wl1[k0];
  }

#pragma unroll
  for (int ks = 0; ks < 32; ++ks) {
    // consume current step (copy out before the slot is re-filled)
    short8_t bh, bl;
    split8(pxa[ks & 3], pxb[ks & 3], bh, bl);
    short8_t a0h = pa0h[ks & 1], a0l = pa0l[ks & 1];
    short8_t a1h = pa1h[ks & 1], a1l = pa1l[ks & 1];
    // issue prefetches early so they overlap the MFMAs below
    if (ks + 4 < 32) {
      const int kn = ((ks + 4) << 4) + (hk << 3);
      pxa[ks & 3] = *(const float4*)&xrow[kn];
      pxb[ks & 3] = *(const float4*)&xrow[kn + 4];
    }
    if (ks + 2 < 32) {
      const int kn = ((ks + 2) << 4) + (hk << 3);
      pa0h[ks & 1] = *(const short8_t*)&wh0[kn];
      pa0l[ks & 1] = *(const short8_t*)&wl0[kn];
      pa1h[ks & 1] = *(const short8_t*)&wh1[kn];
      pa1l[ks & 1] = *(const short8_t*)&wl1[kn];
    }
    acc0 = __builtin_amdgcn_mfma_f32_32x32x16_bf16(a0h, bh, acc0, 0, 0, 0);
    acc1 = __builtin_amdgcn_mfma_f32_32x32x16_bf16(a1h, bh, acc1, 0, 0, 0);
    acc0 = __builtin_amdgcn_mfma_f32_32x32x16_bf16(a0h, bl, acc0, 0, 0, 0);
    acc1 = __builtin_amdgcn_mfma_f32_32x32x16_bf16(a1h, bl, acc1, 0, 0, 0);
    acc0 = __builtin_amdgcn_mfma_f32_32x32x16_bf16(a0l, bh, acc0, 0, 0, 0);
    acc1 = __builtin_amdgcn_mfma_f32_32x32x16_bf16(a1l, bh, acc1, 0, 0, 0);
  }

  // epilogue: bias + coalesced stores. C/D: col(lane&31)=l, m=(r&3)+8*(r>>2)+4*hk
  const int b    = lrow >> 10;
  const int lloc = lrow & 1023;
  float* __restrict__ p = proj + (size_t)in * PROJ_N + ((size_t)(b * 64) << 10) + lloc;
#pragma unroll
  for (int r = 0; r < 16; ++r) {
    const int m = (r & 3) + ((r >> 2) << 3) + (hk << 2);
    p[(size_t)m << 10]        = acc0[r] + bq[m];
    p[(size_t)(m + 32) << 10] = acc1[r] + bq[m + 32];
  }
}

// ---------------------------------------------------------------------------
// Kernel B: circular correlation via SPLIT-PRECISION bf16 MFMA + top-13 +
// softmax + FUSED v-aggregation. One block per (b,d) pair; 4 waves split K.
//   corr[col + 32*row] = sum_kk k_ext[1024+kk-32row] * q_ext[kk+col]
// Then agg[l] = sum_k w_k * v[(l+idx_k) mod 1024]  (v staged in reused LDS).
// ---------------------------------------------------------------------------
__global__ __launch_bounds__(256) void corr_mfma_kernel(
    const float* __restrict__ qp, const float* __restrict__ kp,
    const float* __restrict__ vp, float* __restrict__ agg) {
  __shared__ __align__(16) short qh[2048];   // q_ext hi, linear lines
  __shared__ __align__(16) short ql[2048];   // q_ext lo, linear lines
  __shared__ __align__(16) short kh[2048];   // k_ext hi, line c at phys c^((c>>3)&7)
  __shared__ __align__(16) short kl[2048];   // k_ext lo, swizzled
  __shared__ float corr4[4][1024];           // partials; later reused as vs[2048]
  __shared__ float tv[13];
  __shared__ float sw[13];
  __shared__ int   ts[13];
  __shared__ float rv[4];
  __shared__ int   rs[4];
  __shared__ int   bsh;

  const int pair = blockIdx.x;
  const int tid  = threadIdx.x;
  const int w    = tid >> 6;
  const int lane = tid & 63;
  const int row  = lane & 31;
  const int hk2  = lane >> 5;

  const float* __restrict__ qg = qp + (size_t)pair * 1024;
  const float* __restrict__ kg = kp + (size_t)pair * 1024;
  const float* __restrict__ vg = vp + (size_t)pair * 1024;

  // ---- stage q_ext and k_ext as hi/lo bf16 pairs ----
  {
    const int j = (tid << 3) & 1023;          // both exts are periodic copies
    float4 a0 = *(const float4*)&qg[j];
    float4 a1 = *(const float4*)&qg[j + 4];
    short8_t h8, l8;
    split8(a0, a1, h8, l8);
    *(short8_t*)&qh[tid << 3] = h8;
    *(short8_t*)&ql[tid << 3] = l8;
    float4 b0 = *(const float4*)&kg[j];
    float4 b1 = *(const float4*)&kg[j + 4];
    split8(b0, b1, h8, l8);
    const int p = tid ^ ((tid >> 3) & 7);
    *(short8_t*)&kh[p << 3] = h8;
    *(short8_t*)&kl[p << 3] = l8;
  }
  __syncthreads();

  // ---- MFMA over this wave's K-chunk (3 products per step) ----
  floatx16 acc = {0.f,0.f,0.f,0.f,0.f,0.f,0.f,0.f,
                  0.f,0.f,0.f,0.f,0.f,0.f,0.f,0.f};
  const unsigned* __restrict__ qhd = (const unsigned*)qh;
  const unsigned* __restrict__ qld = (const unsigned*)ql;
#pragma unroll
  for (int i = 0; i < 16; ++i) {
    const int k0 = (w << 8) + (i << 4);
    // A fragments: k_ext[1024 + k0 + 8*hk2 - 32*row .. +7]
    const int e0 = 1024 + k0 + (hk2 << 3) - (row << 5);
    const int c  = e0 >> 3;
    const int p  = c ^ ((c >> 3) & 7);
    short8_t ah = *(const short8_t*)&kh[p << 3];
    short8_t al = *(const short8_t*)&kl[p << 3];
    // B fragments: q_ext[k0 + 8*hk2 + row .. +7]  (element-misaligned)
    const int s0 = k0 + (hk2 << 3) + row;
    const int d0 = s0 >> 1;
    const unsigned sh = (s0 & 1) << 4;
    unsigned w0 = qhd[d0 + 0], w1 = qhd[d0 + 1], w2 = qhd[d0 + 2],
             w3 = qhd[d0 + 3], w4 = qhd[d0 + 4];
    uint4_t buh = { __builtin_amdgcn_alignbit(w1, w0, sh),
                    __builtin_amdgcn_alignbit(w2, w1, sh),
                    __builtin_amdgcn_alignbit(w3, w2, sh),
                    __builtin_amdgcn_alignbit(w4, w3, sh) };
    unsigned x0 = qld[d0 + 0], x1 = qld[d0 + 1], x2 = qld[d0 + 2],
             x3 = qld[d0 + 3], x4 = qld[d0 + 4];
    uint4_t bul = { __builtin_amdgcn_alignbit(x1, x0, sh),
                    __builtin_amdgcn_alignbit(x2, x1, sh),
                    __builtin_amdgcn_alignbit(x3, x2, sh),
                    __builtin_amdgcn_alignbit(x4, x3, sh) };
    short8_t bh = __builtin_bit_cast(short8_t, buh);
    short8_t bl = __builtin_bit_cast(short8_t, bul);
    acc = __builtin_amdgcn_mfma_f32_32x32x16_bf16(ah, bh, acc, 0, 0, 0);
    acc = __builtin_amdgcn_mfma_f32_32x32x16_bf16(ah, bl, acc, 0, 0, 0);
    acc = __builtin_amdgcn_mfma_f32_32x32x16_bf16(al, bh, acc, 0, 0, 0);
  }

  // ---- write partials; C/D layout: col=lane&31, row=(r&3)+8*(r>>2)+4*hk2 ----
#pragma unroll
  for (int r = 0; r < 16; ++r) {
    const int srow = (r & 3) + ((r >> 2) << 3) + (hk2 << 2);
    corr4[w][(srow << 5) | row] = acc[r];
  }
  __syncthreads();

  // ---- issue v loads early (T14): latency hides under reduce+topk ----
  float4 vl0 = *(const float4*)&vg[(4 * tid) & 1023];
  float4 vl1 = *(const float4*)&vg[(4 * (tid + 256)) & 1023];

  // ---- reduce 4 partials; each thread owns s = {tid, +256, +512, +768} ----
  float v0 = corr4[0][tid]       + corr4[1][tid]       + corr4[2][tid]       + corr4[3][tid];
  float v1 = corr4[0][tid + 256] + corr4[1][tid + 256] + corr4[2][tid + 256] + corr4[3][tid + 256];
  float v2 = corr4[0][tid + 512] + corr4[1][tid + 512] + corr4[2][tid + 512] + corr4[3][tid + 512];
  float v3 = corr4[0][tid + 768] + corr4[1][tid + 768] + corr4[2][tid + 768] + corr4[3][tid + 768];
  __syncthreads();   // all corr4 reads done; safe to reuse as vs

  // ---- stage v (duplicated to 2048) into reused corr4 space ----
  float* vs = &corr4[0][0];
  *(float4*)&vs[4 * tid]         = vl0;
  *(float4*)&vs[4 * (tid + 256)] = vl1;

  // ---- top-13 via iterative block argmax ----
  for (int r = 0; r < 13; ++r) {
    float bv = v0; int bs = tid;
    if (v1 > bv) { bv = v1; bs = tid + 256; }
    if (v2 > bv) { bv = v2; bs = tid + 512; }
    if (v3 > bv) { bv = v3; bs = tid + 768; }
#pragma unroll
    for (int off = 32; off >= 1; off >>= 1) {
      float ov = __shfl_xor(bv, off, 64);
      int   os = __shfl_xor(bs, off, 64);
      if (ov > bv || (ov == bv && os < bs)) { bv = ov; bs = os; }
    }
    if (lane == 0) { rv[w] = bv; rs[w] = bs; }
    __syncthreads();
    if (tid == 0) {
      float cv = rv[0]; int cs = rs[0];
#pragma unroll
      for (int u = 1; u < 4; ++u)
        if (rv[u] > cv || (rv[u] == cv && rs[u] < cs)) { cv = rv[u]; cs = rs[u]; }
      tv[r] = cv; ts[r] = cs; bsh = cs;
    }
    __syncthreads();
    const int bw = bsh;
    if ((bw & 255) == tid) {
      const int slot = bw >> 8;
      if      (slot == 0) v0 = -FLT_MAX;
      else if (slot == 1) v1 = -FLT_MAX;
      else if (slot == 2) v2 = -FLT_MAX;
      else                v3 = -FLT_MAX;
    }
  }

  // ---- softmax over the 13 values (thread 0) ----
  if (tid == 0) {
    const float mx = tv[0];
    float e[13]; float s = 0.f;
#pragma unroll
    for (int k2 = 0; k2 < 13; ++k2) { e[k2] = __expf(tv[k2] - mx); s += e[k2]; }
    const float inv = 1.f / s;
#pragma unroll
    for (int k2 = 0; k2 < 13; ++k2) sw[k2] = e[k2] * inv;
  }
  __syncthreads();

  // ---- fused aggregation: agg[l] = sum_k w_k * v[(l+idx_k) mod 1024] ----
  float r0 = 0.f, r1 = 0.f, r2 = 0.f, r3 = 0.f;
#pragma unroll
  for (int k2 = 0; k2 < 13; ++k2) {
    const float wk = sw[k2];
    const int   ik = ts[k2];
    r0 += wk * vs[tid        + ik];
    r1 += wk * vs[tid + 256  + ik];
    r2 += wk * vs[tid + 512  + ik];
    r3 += wk * vs[tid + 768  + ik];
  }
  float* __restrict__ ag = agg + (size_t)pair * 1024;
  ag[tid] = r0; ag[tid + 256] = r1; ag[tid + 512] = r2; ag[tid + 768] = r3;
}

// ---------------------------------------------------------------------------
// Kernel D: out[b][l][h*64+d] = agg[b*64+d][l]  (transpose + 8x head copy)
// ---------------------------------------------------------------------------
__global__ __launch_bounds__(256) void out_kernel(
    const float* __restrict__ agg, float* __restrict__ out) {
  __shared__ float tile[64][65];
  const int blk = blockIdx.x;
  const int b = blk >> 4, lt = blk & 15;
  const int l0 = lt * 64;
  const int t = threadIdx.x;
  const int j = t & 63, qq = t >> 6;

#pragma unroll
  for (int p = 0; p < 16; ++p) {
    const int d = p * 4 + qq;
    tile[d][j] = agg[(size_t)(b * 64 + d) * 1024 + l0 + j];
  }
  __syncthreads();
#pragma unroll
  for (int p = 0; p < 16; ++p) {
    const int jj = p * 4 + qq;
    const float val = tile[j][jj];
    const size_t rowbase = ((size_t)(b * 1024 + l0 + jj)) * 512;
#pragma unroll
    for (int h = 0; h < 8; ++h)
      out[rowbase + h * 64 + j] = val;
  }
}

// ---------------------------------------------------------------------------
extern "C" void kernel_launch(void* const* d_in, const int* in_sizes, int n_in,
                              void* d_out, int out_size, void* d_ws, size_t ws_size,
                              hipStream_t stream) {
  const float* Q  = (const float*)d_in[0];
  const float* K  = (const float*)d_in[1];
  const float* V  = (const float*)d_in[2];
  const float* Wq = (const float*)d_in[3];
  const float* bq = (const float*)d_in[4];
  float* out = (float*)d_out;
  float* ws  = (float*)d_ws;

  float* proj = ws;                               // 3 * 1048576 floats
  float* agg  = ws + (size_t)3 * PROJ_N;          // 1048576 floats
  // Wt_h/Wt_l (128 KB) live at agg's base: read only by proj_kernel, then
  // overwritten by corr's agg stores (kernels are stream-serialized).
  unsigned short* Wth = (unsigned short*)agg;     // 64*512 shorts
  unsigned short* Wtl = Wth + 64 * 512;

  wtrans_kernel<<<128, 256, 0, stream>>>(Wq, Wth, Wtl);
  proj_kernel<<<768, 128, 0, stream>>>(Q, K, V, Wth, Wtl, bq, proj);
  corr_mfma_kernel<<<1024, 256, 0, stream>>>(proj, proj + PROJ_N,
                                             proj + (size_t)2 * PROJ_N, agg);
  out_kernel<<<256, 256, 0, stream>>>(agg, out);
}

// Round 9
// 181.060 us; speedup vs baseline: 1.2100x; 1.0638x over previous
//
#include <hip/hip_runtime.h>
#include <float.h>
#include <math.h>
#include <stdint.h>

// Problem constants: B=16, L=1024, D=512, DH=64, H=8, ktop=13
#define PROJ_N (16*64*1024)   // 1048576 floats per projected tensor (layout [b*64+d][l])

using short8_t  = __attribute__((ext_vector_type(8)))  short;
using uint4_t   = __attribute__((ext_vector_type(4)))  unsigned;
using floatx16  = __attribute__((ext_vector_type(16))) float;

typedef __attribute__((address_space(3))) uint32_t lds_u32_t;
typedef __attribute__((address_space(1))) const uint32_t glb_u32_t;

// ---------------------------------------------------------------------------
// bf16 helpers: RNE round, pack, and hi/lo split (x = hi + lo)
// ---------------------------------------------------------------------------
__device__ __forceinline__ unsigned bf16r(float x) {
  unsigned u = __float_as_uint(x);
  return (u + 0x7FFFu + ((u >> 16) & 1u)) >> 16;
}
__device__ __forceinline__ unsigned pk_bf16(float x, float y) {
  return bf16r(x) | (bf16r(y) << 16);
}
// split 8 floats into hi/lo bf16 short8 fragments
__device__ __forceinline__ void split8(float4 a, float4 b, short8_t& h, short8_t& l) {
  float f[8] = {a.x, a.y, a.z, a.w, b.x, b.y, b.z, b.w};
  unsigned hp[4], lp[4];
#pragma unroll
  for (int j = 0; j < 4; ++j) {
    unsigned h0 = bf16r(f[2*j]), h1 = bf16r(f[2*j+1]);
    hp[j] = h0 | (h1 << 16);
    float l0 = f[2*j]   - __uint_as_float(h0 << 16);
    float l1 = f[2*j+1] - __uint_as_float(h1 << 16);
    lp[j] = pk_bf16(l0, l1);
  }
  uint4_t hv = {hp[0], hp[1], hp[2], hp[3]};
  uint4_t lv = {lp[0], lp[1], lp[2], lp[3]};
  h = __builtin_bit_cast(short8_t, hv);
  l = __builtin_bit_cast(short8_t, lv);
}

// ---------------------------------------------------------------------------
// Kernel W: Wt_h/Wt_l[d][k] = hi/lo bf16 split of Wq[k][d]  (64 x 512, 128 KB)
// ---------------------------------------------------------------------------
__global__ __launch_bounds__(256) void wtrans_kernel(
    const float* __restrict__ Wq, unsigned short* __restrict__ Wth,
    unsigned short* __restrict__ Wtl) {
  const int tg = blockIdx.x * 256 + threadIdx.x;   // 0..32767
  const int d = tg & 63, k = tg >> 6;
  const float x = Wq[k * 64 + d];
  const unsigned h = bf16r(x);
  const float lo = x - __uint_as_float(h << 16);
  Wth[d * 512 + k] = (unsigned short)h;
  Wtl[d * 512 + k] = (unsigned short)bf16r(lo);
}

// ---------------------------------------------------------------------------
// Kernel A: proj = X @ Wq + bq via split-precision bf16 MFMA.
// m97-STYLE STRUCTURE: X staged into double-buffered LDS via async
// global_load_lds_dwordx4 (the DMA cannot be compiler-sunk, unlike every
// register-prefetch attempt in rounds 5-7). W read direct from L2.
// grid = 768 (3 inputs x 256 tiles of 64 l), block = 128 (2 waves x 32 l),
// K-step = 64 (8 steps). LDS 2 x 16 KB fp32 tile, pair-XOR-swizzled via the
// GLOBAL source address (LDS dest must stay linear: wave base + lane*16).
//   logical (row r, pair p(0..7 of 8 floats), e) -> phys pair = p ^ (r&7)
// Read side: 2x ds_read_b128 per fragment at <=4-way bank conflict.
// ---------------------------------------------------------------------------
__global__ __launch_bounds__(128) void proj_kernel(
    const float* __restrict__ Q, const float* __restrict__ K,
    const float* __restrict__ V, const unsigned short* __restrict__ Wth,
    const unsigned short* __restrict__ Wtl, const float* __restrict__ bq,
    float* __restrict__ proj) {
  __shared__ __align__(16) float xs[2][4096];   // 2 x 16 KB

  const int blk  = blockIdx.x;
  const int in   = blk >> 8;            // 0..2
  const int row0 = (blk & 255) << 6;    // global row (b*1024 + l), 64-row tile
  const float* __restrict__ X = (in == 0) ? Q : (in == 1 ? K : V);

  const int tid  = threadIdx.x;
  const int w    = tid >> 6;
  const int lane = tid & 63;
  const int col  = lane & 31;   // l within wave tile / d-row for A
  const int hk   = lane >> 5;
  const int r    = (w << 5) + col;      // this lane's logical row in the tile

  floatx16 acc0 = {0.f,0.f,0.f,0.f,0.f,0.f,0.f,0.f,
                   0.f,0.f,0.f,0.f,0.f,0.f,0.f,0.f};
  floatx16 acc1 = {0.f,0.f,0.f,0.f,0.f,0.f,0.f,0.f,
                   0.f,0.f,0.f,0.f,0.f,0.f,0.f,0.f};

  // ---- async stage of one 64x64 K-subtile (16 KB) into xs[bufidx] ----
  // phys float idx f = i*512 + tid*4 ; row=f>>6, off=f&63; logical pair
  // p = (off>>3) ^ (row&7); global k = k0 + p*8 + (off&7)  [off&3==0].
  auto STAGE = [&](int kt, int bufidx) {
    const int k0 = kt << 6;
#pragma unroll
    for (int i = 0; i < 8; ++i) {
      const int f   = i * 512 + tid * 4;
      const int row = f >> 6;
      const int off = f & 63;
      const int p   = ((off >> 3) ^ row) & 7;
      const float* gsrc = &X[(size_t)(row0 + row) * 512 + k0 + (p << 3) + (off & 7)];
      // LDS dest: wave-uniform base (floats): i*512 + w*256 ; HW adds lane*16B
      const float* lbase = &xs[bufidx][i * 512 + (w << 8)];
      __builtin_amdgcn_global_load_lds((glb_u32_t*)(uintptr_t)gsrc,
                                       (lds_u32_t*)(uintptr_t)lbase, 16, 0, 0);
    }
  };

  STAGE(0, 0);
#pragma unroll
  for (int kt = 0; kt < 8; ++kt) {
    const int cur = kt & 1;
    if (kt < 7) STAGE(kt + 1, cur ^ 1);
    __syncthreads();   // vmcnt(0) drain: xs[cur] staged & visible

    const int k0 = kt << 6;
#pragma unroll
    for (int kc = 0; kc < 4; ++kc) {
      // B fragment: X rows, k = k0 + kc*16 + hk*8 .. +7 (swizzled pair read)
      const int pp = (((kc << 1) | hk) ^ (r & 7)) & 7;
      const float* src = &xs[cur][(r << 6) + (pp << 3)];
      float4 xa = *(const float4*)&src[0];
      float4 xb = *(const float4*)&src[4];
      short8_t bh, bl;
      split8(xa, xb, bh, bl);
      // A fragments: Wt[d][k], d-row = col / col+32, direct from L2
      const int kk = k0 + (kc << 4) + (hk << 3);
      short8_t a0h = *(const short8_t*)&Wth[(size_t)col * 512 + kk];
      short8_t a0l = *(const short8_t*)&Wtl[(size_t)col * 512 + kk];
      short8_t a1h = *(const short8_t*)&Wth[(size_t)(col + 32) * 512 + kk];
      short8_t a1l = *(const short8_t*)&Wtl[(size_t)(col + 32) * 512 + kk];
      acc0 = __builtin_amdgcn_mfma_f32_32x32x16_bf16(a0h, bh, acc0, 0, 0, 0);
      acc1 = __builtin_amdgcn_mfma_f32_32x32x16_bf16(a1h, bh, acc1, 0, 0, 0);
      acc0 = __builtin_amdgcn_mfma_f32_32x32x16_bf16(a0h, bl, acc0, 0, 0, 0);
      acc1 = __builtin_amdgcn_mfma_f32_32x32x16_bf16(a1h, bl, acc1, 0, 0, 0);
      acc0 = __builtin_amdgcn_mfma_f32_32x32x16_bf16(a0l, bh, acc0, 0, 0, 0);
      acc1 = __builtin_amdgcn_mfma_f32_32x32x16_bf16(a1l, bh, acc1, 0, 0, 0);
    }
    __syncthreads();   // all reads of xs[cur^1]'s future slot done
  }

  // epilogue: bias + coalesced stores. C/D: col(lane&31)=l, m=(r&3)+8*(r>>2)+4*hk
  const int lrow = row0 + (w << 5) + col;
  const int b    = lrow >> 10;
  const int lloc = lrow & 1023;
  float* __restrict__ p = proj + (size_t)in * PROJ_N + ((size_t)(b * 64) << 10) + lloc;
#pragma unroll
  for (int rr = 0; rr < 16; ++rr) {
    const int m = (rr & 3) + ((rr >> 2) << 3) + (hk << 2);
    p[(size_t)m << 10]        = acc0[rr] + bq[m];
    p[(size_t)(m + 32) << 10] = acc1[rr] + bq[m + 32];
  }
}

// ---------------------------------------------------------------------------
// Kernel B: circular correlation via SPLIT-PRECISION bf16 MFMA + top-13 +
// softmax + FUSED v-aggregation. One block per (b,d) pair; 4 waves split K.
//   corr[col + 32*row] = sum_kk k_ext[1024+kk-32row] * q_ext[kk+col]
// Then agg[l] = sum_k w_k * v[(l+idx_k) mod 1024]  (v staged in reused LDS).
// ---------------------------------------------------------------------------
__global__ __launch_bounds__(256) void corr_mfma_kernel(
    const float* __restrict__ qp, const float* __restrict__ kp,
    const float* __restrict__ vp, float* __restrict__ agg) {
  __shared__ __align__(16) short qh[2048];   // q_ext hi, linear lines
  __shared__ __align__(16) short ql[2048];   // q_ext lo, linear lines
  __shared__ __align__(16) short kh[2048];   // k_ext hi, line c at phys c^((c>>3)&7)
  __shared__ __align__(16) short kl[2048];   // k_ext lo, swizzled
  __shared__ float corr4[4][1024];           // partials; later reused as vs[2048]
  __shared__ float tv[13];
  __shared__ float sw[13];
  __shared__ int   ts[13];
  __shared__ float rv[4];
  __shared__ int   rs[4];
  __shared__ int   bsh;

  const int pair = blockIdx.x;
  const int tid  = threadIdx.x;
  const int w    = tid >> 6;
  const int lane = tid & 63;
  const int row  = lane & 31;
  const int hk2  = lane >> 5;

  const float* __restrict__ qg = qp + (size_t)pair * 1024;
  const float* __restrict__ kg = kp + (size_t)pair * 1024;
  const float* __restrict__ vg = vp + (size_t)pair * 1024;

  // ---- stage q_ext and k_ext as hi/lo bf16 pairs ----
  {
    const int j = (tid << 3) & 1023;          // both exts are periodic copies
    float4 a0 = *(const float4*)&qg[j];
    float4 a1 = *(const float4*)&qg[j + 4];
    short8_t h8, l8;
    split8(a0, a1, h8, l8);
    *(short8_t*)&qh[tid << 3] = h8;
    *(short8_t*)&ql[tid << 3] = l8;
    float4 b0 = *(const float4*)&kg[j];
    float4 b1 = *(const float4*)&kg[j + 4];
    split8(b0, b1, h8, l8);
    const int p = tid ^ ((tid >> 3) & 7);
    *(short8_t*)&kh[p << 3] = h8;
    *(short8_t*)&kl[p << 3] = l8;
  }
  __syncthreads();

  // ---- MFMA over this wave's K-chunk (3 products per step) ----
  floatx16 acc = {0.f,0.f,0.f,0.f,0.f,0.f,0.f,0.f,
                  0.f,0.f,0.f,0.f,0.f,0.f,0.f,0.f};
  const unsigned* __restrict__ qhd = (const unsigned*)qh;
  const unsigned* __restrict__ qld = (const unsigned*)ql;
#pragma unroll
  for (int i = 0; i < 16; ++i) {
    const int k0 = (w << 8) + (i << 4);
    // A fragments: k_ext[1024 + k0 + 8*hk2 - 32*row .. +7]
    const int e0 = 1024 + k0 + (hk2 << 3) - (row << 5);
    const int c  = e0 >> 3;
    const int p  = c ^ ((c >> 3) & 7);
    short8_t ah = *(const short8_t*)&kh[p << 3];
    short8_t al = *(const short8_t*)&kl[p << 3];
    // B fragments: q_ext[k0 + 8*hk2 + row .. +7]  (element-misaligned)
    const int s0 = k0 + (hk2 << 3) + row;
    const int d0 = s0 >> 1;
    const unsigned sh = (s0 & 1) << 4;
    unsigned w0 = qhd[d0 + 0], w1 = qhd[d0 + 1], w2 = qhd[d0 + 2],
             w3 = qhd[d0 + 3], w4 = qhd[d0 + 4];
    uint4_t buh = { __builtin_amdgcn_alignbit(w1, w0, sh),
                    __builtin_amdgcn_alignbit(w2, w1, sh),
                    __builtin_amdgcn_alignbit(w3, w2, sh),
                    __builtin_amdgcn_alignbit(w4, w3, sh) };
    unsigned x0 = qld[d0 + 0], x1 = qld[d0 + 1], x2 = qld[d0 + 2],
             x3 = qld[d0 + 3], x4 = qld[d0 + 4];
    uint4_t bul = { __builtin_amdgcn_alignbit(x1, x0, sh),
                    __builtin_amdgcn_alignbit(x2, x1, sh),
                    __builtin_amdgcn_alignbit(x3, x2, sh),
                    __builtin_amdgcn_alignbit(x4, x3, sh) };
    short8_t bh = __builtin_bit_cast(short8_t, buh);
    short8_t bl = __builtin_bit_cast(short8_t, bul);
    acc = __builtin_amdgcn_mfma_f32_32x32x16_bf16(ah, bh, acc, 0, 0, 0);
    acc = __builtin_amdgcn_mfma_f32_32x32x16_bf16(ah, bl, acc, 0, 0, 0);
    acc = __builtin_amdgcn_mfma_f32_32x32x16_bf16(al, bh, acc, 0, 0, 0);
  }

  // ---- write partials; C/D layout: col=lane&31, row=(r&3)+8*(r>>2)+4*hk2 ----
#pragma unroll
  for (int r = 0; r < 16; ++r) {
    const int srow = (r & 3) + ((r >> 2) << 3) + (hk2 << 2);
    corr4[w][(srow << 5) | row] = acc[r];
  }
  __syncthreads();

  // ---- issue v loads early (T14): latency hides under reduce+topk ----
  float4 vl0 = *(const float4*)&vg[(4 * tid) & 1023];
  float4 vl1 = *(const float4*)&vg[(4 * (tid + 256)) & 1023];

  // ---- reduce 4 partials; each thread owns s = {tid, +256, +512, +768} ----
  float v0 = corr4[0][tid]       + corr4[1][tid]       + corr4[2][tid]       + corr4[3][tid];
  float v1 = corr4[0][tid + 256] + corr4[1][tid + 256] + corr4[2][tid + 256] + corr4[3][tid + 256];
  float v2 = corr4[0][tid + 512] + corr4[1][tid + 512] + corr4[2][tid + 512] + corr4[3][tid + 512];
  float v3 = corr4[0][tid + 768] + corr4[1][tid + 768] + corr4[2][tid + 768] + corr4[3][tid + 768];
  __syncthreads();   // all corr4 reads done; safe to reuse as vs

  // ---- stage v (duplicated to 2048) into reused corr4 space ----
  float* vs = &corr4[0][0];
  *(float4*)&vs[4 * tid]         = vl0;
  *(float4*)&vs[4 * (tid + 256)] = vl1;

  // ---- top-13 via iterative block argmax ----
  for (int r = 0; r < 13; ++r) {
    float bv = v0; int bs = tid;
    if (v1 > bv) { bv = v1; bs = tid + 256; }
    if (v2 > bv) { bv = v2; bs = tid + 512; }
    if (v3 > bv) { bv = v3; bs = tid + 768; }
#pragma unroll
    for (int off = 32; off >= 1; off >>= 1) {
      float ov = __shfl_xor(bv, off, 64);
      int   os = __shfl_xor(bs, off, 64);
      if (ov > bv || (ov == bv && os < bs)) { bv = ov; bs = os; }
    }
    if (lane == 0) { rv[w] = bv; rs[w] = bs; }
    __syncthreads();
    if (tid == 0) {
      float cv = rv[0]; int cs = rs[0];
#pragma unroll
      for (int u = 1; u < 4; ++u)
        if (rv[u] > cv || (rv[u] == cv && rs[u] < cs)) { cv = rv[u]; cs = rs[u]; }
      tv[r] = cv; ts[r] = cs; bsh = cs;
    }
    __syncthreads();
    const int bw = bsh;
    if ((bw & 255) == tid) {
      const int slot = bw >> 8;
      if      (slot == 0) v0 = -FLT_MAX;
      else if (slot == 1) v1 = -FLT_MAX;
      else if (slot == 2) v2 = -FLT_MAX;
      else                v3 = -FLT_MAX;
    }
  }

  // ---- softmax over the 13 values (thread 0) ----
  if (tid == 0) {
    const float mx = tv[0];
    float e[13]; float s = 0.f;
#pragma unroll
    for (int k2 = 0; k2 < 13; ++k2) { e[k2] = __expf(tv[k2] - mx); s += e[k2]; }
    const float inv = 1.f / s;
#pragma unroll
    for (int k2 = 0; k2 < 13; ++k2) sw[k2] = e[k2] * inv;
  }
  __syncthreads();

  // ---- fused aggregation: agg[l] = sum_k w_k * v[(l+idx_k) mod 1024] ----
  float r0 = 0.f, r1 = 0.f, r2 = 0.f, r3 = 0.f;
#pragma unroll
  for (int k2 = 0; k2 < 13; ++k2) {
    const float wk = sw[k2];
    const int   ik = ts[k2];
    r0 += wk * vs[tid        + ik];
    r1 += wk * vs[tid + 256  + ik];
    r2 += wk * vs[tid + 512  + ik];
    r3 += wk * vs[tid + 768  + ik];
  }
  float* __restrict__ ag = agg + (size_t)pair * 1024;
  ag[tid] = r0; ag[tid + 256] = r1; ag[tid + 512] = r2; ag[tid + 768] = r3;
}

// ---------------------------------------------------------------------------
// Kernel D: out[b][l][h*64+d] = agg[b*64+d][l]  (transpose + 8x head copy)
// ---------------------------------------------------------------------------
__global__ __launch_bounds__(256) void out_kernel(
    const float* __restrict__ agg, float* __restrict__ out) {
  __shared__ float tile[64][65];
  const int blk = blockIdx.x;
  const int b = blk >> 4, lt = blk & 15;
  const int l0 = lt * 64;
  const int t = threadIdx.x;
  const int j = t & 63, qq = t >> 6;

#pragma unroll
  for (int p = 0; p < 16; ++p) {
    const int d = p * 4 + qq;
    tile[d][j] = agg[(size_t)(b * 64 + d) * 1024 + l0 + j];
  }
  __syncthreads();
#pragma unroll
  for (int p = 0; p < 16; ++p) {
    const int jj = p * 4 + qq;
    const float val = tile[j][jj];
    const size_t rowbase = ((size_t)(b * 1024 + l0 + jj)) * 512;
#pragma unroll
    for (int h = 0; h < 8; ++h)
      out[rowbase + h * 64 + j] = val;
  }
}

// ---------------------------------------------------------------------------
extern "C" void kernel_launch(void* const* d_in, const int* in_sizes, int n_in,
                              void* d_out, int out_size, void* d_ws, size_t ws_size,
                              hipStream_t stream) {
  const float* Q  = (const float*)d_in[0];
  const float* K  = (const float*)d_in[1];
  const float* V  = (const float*)d_in[2];
  const float* Wq = (const float*)d_in[3];
  const float* bq = (const float*)d_in[4];
  float* out = (float*)d_out;
  float* ws  = (float*)d_ws;

  float* proj = ws;                               // 3 * 1048576 floats
  float* agg  = ws + (size_t)3 * PROJ_N;          // 1048576 floats
  // Wt_h/Wt_l (128 KB) live at agg's base: read only by proj_kernel, then
  // overwritten by corr's agg stores (kernels are stream-serialized).
  unsigned short* Wth = (unsigned short*)agg;     // 64*512 shorts
  unsigned short* Wtl = Wth + 64 * 512;

  wtrans_kernel<<<128, 256, 0, stream>>>(Wq, Wth, Wtl);
  proj_kernel<<<768, 128, 0, stream>>>(Q, K, V, Wth, Wtl, bq, proj);
  corr_mfma_kernel<<<1024, 256, 0, stream>>>(proj, proj + PROJ_N,
                                             proj + (size_t)2 * PROJ_N, agg);
  out_kernel<<<256, 256, 0, stream>>>(agg, out);
}